// Round 5
// baseline (118.259 us; speedup 1.0000x reference)
//
#include <hip/hip_runtime.h>
#include <hip/hip_bf16.h>

constexpr int kT = 32768;   // tokens = B*N
constexpr int kD = 128;
constexpr int kH = 256;
constexpr int kE = 16;

typedef __bf16 bf16x8 __attribute__((ext_vector_type(8)));
typedef unsigned short u16x8 __attribute__((ext_vector_type(8)));
typedef float f32x4 __attribute__((ext_vector_type(4)));

#define LDX 136   // x-tile LDS row stride (ushort) = 128 + 8 pad
#define LDH 264   // h-tile LDS row stride (ushort) = 256 + 8 pad

constexpr int NB_TP   = 272;     // transpose tiles (17 W1-like + 17 W2-like, 8 each)
constexpr int NB_GATE = kT / 64; // 512
constexpr int CNT_STRIDE = 32;   // counters padded to 128 B (own cache line)
constexpr int MOE_GRID = 768;    // 3 blocks/CU, expert-resident

__device__ __forceinline__ unsigned short f2bf(float f) {
  unsigned int u = __float_as_uint(f);
  u += 0x7FFFu + ((u >> 16) & 1u);   // round-to-nearest-even
  return (unsigned short)(u >> 16);
}
__device__ __forceinline__ void eostore(float* p, float v) { *p = v; }
__device__ __forceinline__ void eostore(unsigned short* p, float v) { *p = f2bf(v); }
__device__ __forceinline__ float eoload(const float* p) { return *p; }
__device__ __forceinline__ float eoload(const unsigned short* p) {
  unsigned int u = (unsigned int)(*p) << 16; return __uint_as_float(u);
}

// ---------- fused front-end: weight transpose | gating (+x cast, tpos) ------
__global__ __launch_bounds__(256) void front_kernel(
    const float* __restrict__ x, const float* __restrict__ Wg,
    const float* __restrict__ bg,
    const float* __restrict__ W1, const float* __restrict__ W2,
    const float* __restrict__ Wu1, const float* __restrict__ Wu2,
    unsigned short* __restrict__ xb, unsigned short* __restrict__ W1t,
    unsigned short* __restrict__ W2t, unsigned short* __restrict__ Wu1t,
    unsigned short* __restrict__ Wu2t,
    int* __restrict__ cnt, int* __restrict__ btok, float* __restrict__ bgate,
    int* __restrict__ tpos)
{
  __shared__ __align__(16) char smem[46848];
  const int tid = threadIdx.x;
  const int b = blockIdx.x;

  if (b < NB_TP) {
    // ---- LDS-tiled transpose fp32 [R][C] -> bf16 [C][R], 64x64 tiles
    int bb = b;
    const float* src; unsigned short* dst; int R, C, r0, c0;
    if (bb < 136) {                 // W1-like: [128][256] -> [256][128]
      int m = bb >> 3, t8 = bb & 7;
      R = 128; C = 256;
      src = (m < 16) ? W1 + (size_t)m * 32768 : Wu1;
      dst = (m < 16) ? W1t + (size_t)m * 32768 : Wu1t;
      r0 = (t8 & 1) * 64; c0 = (t8 >> 1) * 64;
    } else {                        // W2-like: [256][128] -> [128][256]
      bb -= 136;
      int m = bb >> 3, t8 = bb & 7;
      R = 256; C = 128;
      src = (m < 16) ? W2 + (size_t)m * 32768 : Wu2;
      dst = (m < 16) ? W2t + (size_t)m * 32768 : Wu2t;
      r0 = (t8 >> 1) * 64; c0 = (t8 & 1) * 64;
    }
    unsigned short (*tl)[72] = reinterpret_cast<unsigned short(*)[72]>(smem);
#pragma unroll
    for (int i = 0; i < 4; ++i) {
      int s = i * 256 + tid;
      int r = s >> 4, c4 = s & 15;
      float4 v = *reinterpret_cast<const float4*>(&src[(size_t)(r0 + r) * C + c0 + c4 * 4]);
      tl[c4 * 4 + 0][r] = f2bf(v.x);
      tl[c4 * 4 + 1][r] = f2bf(v.y);
      tl[c4 * 4 + 2][r] = f2bf(v.z);
      tl[c4 * 4 + 3][r] = f2bf(v.w);
    }
    __syncthreads();
#pragma unroll
    for (int i = 0; i < 2; ++i) {
      int s = i * 256 + tid;
      int c = s >> 3, seg = s & 7;
      uint4 v = *reinterpret_cast<const uint4*>(&tl[c][seg * 8]);
      *reinterpret_cast<uint4*>(&dst[(size_t)(c0 + c) * R + r0 + seg * 8]) = v;
    }
    return;
  }

  // ---- gating: logits (fp64, ILP), top-2, scatter + x cast
  {
    float* sWt = reinterpret_cast<float*>(smem);            // [16][132]
    float* sX  = reinterpret_cast<float*>(smem + 8448);     // [64][132]
    float* sL  = reinterpret_cast<float*>(smem + 42240);    // [64][17]
    int* hcnt  = reinterpret_cast<int*>(smem + 46592);      // [16]
    int* hbase = reinterpret_cast<int*>(smem + 46656);      // [16]
    int* hb16  = reinterpret_cast<int*>(smem + 46720);      // [1]
    const int t0 = (b - NB_TP) * 64;

    if (tid < kE) hcnt[tid] = 0;
    for (int i = tid; i < kD * kE; i += 256) {              // Wg[d][e] -> sWt[e][d]
      int d = i >> 4, e = i & 15;
      sWt[e * 132 + d] = Wg[i];
    }
    const float4* xv = reinterpret_cast<const float4*>(x + (size_t)t0 * kD);
    for (int i = tid; i < 64 * kD / 4; i += 256) {
      int r = i >> 5, c4 = i & 31;
      *reinterpret_cast<float4*>(&sX[r * 132 + c4 * 4]) = xv[i];
    }
    __syncthreads();

    const int e = tid & 15, tq = tid >> 4;
    const double bgd = (double)bg[e];
    const float4* wr = reinterpret_cast<const float4*>(&sWt[e * 132]);
#pragma unroll
    for (int p = 0; p < 4; ++p) {
      int tt = p * 16 + tq;
      const float4* xr = reinterpret_cast<const float4*>(&sX[tt * 132]);
      double a0 = 0.0, a1 = 0.0, a2 = 0.0, a3 = 0.0;   // 4 independent chains
#pragma unroll
      for (int d8 = 0; d8 < 8; ++d8) {
        float4 xa0 = xr[d8 * 4 + 0], wa0 = wr[d8 * 4 + 0];
        float4 xa1 = xr[d8 * 4 + 1], wa1 = wr[d8 * 4 + 1];
        float4 xa2 = xr[d8 * 4 + 2], wa2 = wr[d8 * 4 + 2];
        float4 xa3 = xr[d8 * 4 + 3], wa3 = wr[d8 * 4 + 3];
        a0 += (double)xa0.x * (double)wa0.x + (double)xa0.y * (double)wa0.y
            + (double)xa0.z * (double)wa0.z + (double)xa0.w * (double)wa0.w;
        a1 += (double)xa1.x * (double)wa1.x + (double)xa1.y * (double)wa1.y
            + (double)xa1.z * (double)wa1.z + (double)xa1.w * (double)wa1.w;
        a2 += (double)xa2.x * (double)wa2.x + (double)xa2.y * (double)wa2.y
            + (double)xa2.z * (double)wa2.z + (double)xa2.w * (double)wa2.w;
        a3 += (double)xa3.x * (double)wa3.x + (double)xa3.y * (double)wa3.y
            + (double)xa3.z * (double)wa3.z + (double)xa3.w * (double)wa3.w;
      }
      sL[tt * 17 + e] = (float)(((a0 + a1) + (a2 + a3)) + bgd);
    }
    // fold x fp32->bf16 cast here (sX already staged)
#pragma unroll
    for (int p = 0; p < 4; ++p) {
      int idx = p * 256 + tid;
      int r = idx >> 4, c8 = (idx & 15) * 8;
      const float* sp = &sX[r * 132 + c8];
      u16x8 v;
#pragma unroll
      for (int j = 0; j < 8; ++j) v[j] = f2bf(sp[j]);
      *reinterpret_cast<u16x8*>(&xb[(size_t)(t0 + r) * kD + c8]) = v;
    }
    __syncthreads();

    int e0 = 0, e1 = 0, lp0 = 0, lp1 = 0;
    float g0 = 0.f, g1 = 0.f;
    const int t = t0 + tid;
    if (tid < 64) {
      float v0 = -3.4e38f, v1 = -3.4e38f;
      for (int i = 0; i < kE; ++i) {
        float v = sL[tid * 17 + i];
        if (v > v0) { v1 = v0; e1 = e0; v0 = v; e0 = i; }
        else if (v > v1) { v1 = v; e1 = i; }
      }
      float r = expf(v1 - v0);
      g0 = 1.f / (1.f + r);
      g1 = 1.f - g0;
      lp0 = atomicAdd(&hcnt[e0], 1);
      lp1 = atomicAdd(&hcnt[e1], 1);
    }
    if (tid == 0) hb16[0] = atomicAdd(&cnt[16 * CNT_STRIDE], 64);
    __syncthreads();
    if (tid < kE)
      hbase[tid] = atomicAdd(&cnt[tid * CNT_STRIDE], hcnt[tid]);
    __syncthreads();
    if (tid < 64) {
      int p0 = hbase[e0] + lp0;
      btok[e0 * kT + p0] = t; bgate[e0 * kT + p0] = g0;
      int p1 = hbase[e1] + lp1;
      btok[e1 * kT + p1] = t; bgate[e1 * kT + p1] = g1;
      int p2 = hb16[0] + tid;                 // universal = bucket 16, weight omega
      btok[16 * kT + p2] = t; bgate[16 * kT + p2] = 1.f - g0;
      tpos[2 * t]     = (e0 << 16) | p0;      // token -> expert slots (for combine)
      tpos[2 * t + 1] = (e1 << 16) | p1;
    }
  }
}

// ---------- expert-resident MoE: weights in VGPRs, PLAIN stores (no atomics)-
template <typename EoT>
__global__ __launch_bounds__(256, 3) void moe_kernel(
    const unsigned short* __restrict__ xb,
    const unsigned short* __restrict__ W1t,
    const unsigned short* __restrict__ W2t,
    const unsigned short* __restrict__ Wu1t,
    const unsigned short* __restrict__ Wu2t,
    const float* __restrict__ b1, const float* __restrict__ b2,
    const float* __restrict__ bu1, const float* __restrict__ bu2,
    const int* __restrict__ cnt, const int* __restrict__ btok,
    const float* __restrict__ bgate,
    EoT* __restrict__ eo, float* __restrict__ out)
{
  __shared__ alignas(16) unsigned short xs[64 * LDX];
  __shared__ alignas(16) unsigned short hs[64 * LDH];
  __shared__ int   tkL[2][64];
  __shared__ float gtL[2][64];
  __shared__ int stl[17];
  __shared__ int sdesc[5];
  const int tid = threadIdx.x;

  // ---- per-block expert allocation: largest-remainder, redundant/deterministic
  if (tid < 17) stl[tid] = cnt[tid * CNT_STRIDE];
  __syncthreads();
  if (tid == 0) {
    int tiles[17], tot = 0;
    for (int i = 0; i < 17; ++i) { tiles[i] = (stl[i] + 63) >> 6; tot += tiles[i]; }
    const int G = MOE_GRID;
    int Be[17], rem[17], sum = 0;
    for (int i = 0; i < 17; ++i) {
      int num = G * tiles[i];
      Be[i] = num / tot;
      rem[i] = num - Be[i] * tot;
      sum += Be[i];
    }
    int R = G - sum;                 // < 17
    for (int k = 0; k < R; ++k) {
      int bi = 0, br = -1;
      for (int i = 0; i < 17; ++i)
        if (rem[i] > br) { br = rem[i]; bi = i; }
      Be[bi] += 1; rem[bi] = -1;
    }
    int bb = blockIdx.x, acc = 0, e = -1, Bi = 0, BeE = 1;
    for (int i = 0; i < 17; ++i) {
      if (bb < acc + Be[i]) { e = i; Bi = bb - acc; BeE = Be[i]; break; }
      acc += Be[i];
    }
    sdesc[0] = e; sdesc[1] = Bi;
    sdesc[2] = (e >= 0) ? ((stl[e] + 63) >> 6) : 0;
    sdesc[3] = BeE;
    int eb = 0;
    if (e >= 0 && e < 16) for (int i = 0; i < e; ++i) eb += stl[i];
    sdesc[4] = eb;                   // eo row base = sum of counts of experts < e
  }
  __syncthreads();
  const int e = sdesc[0], Bi = sdesc[1], tiles_e = sdesc[2], Be = sdesc[3];
  const int eobase = sdesc[4];
  if (e < 0 || Bi >= tiles_e) return;
  const int gcnt = stl[e];
  const int w = tid >> 6, l = tid & 63, lr = l & 15, lg = l >> 4;
  const int gr = tid >> 4, gc = (tid & 15) * 8;
  const f32x4 z4 = {0.f, 0.f, 0.f, 0.f};

  const unsigned short* Bw1 = (e < 16) ? W1t + (size_t)e * kH * kD : Wu1t;
  const unsigned short* Bw2 = (e < 16) ? W2t + (size_t)e * kD * kH : Wu2t;
  const float* bs1 = (e < 16) ? b1 + (size_t)e * kH : bu1;
  const float* bs2 = (e < 16) ? b2 + (size_t)e * kD : bu2;

  // ---- weights -> registers, held across all tiles of this block
  bf16x8 B1[4][4];   // [n][kk]  W1 slice
  bf16x8 B2[2][8];   // [n][kk]  W2 slice
#pragma unroll
  for (int n = 0; n < 4; ++n)
#pragma unroll
    for (int kk = 0; kk < 4; ++kk)
      B1[n][kk] = *reinterpret_cast<const bf16x8*>(
          Bw1 + (size_t)(w * 64 + n * 16 + lr) * kD + kk * 32 + lg * 8);
#pragma unroll
  for (int n = 0; n < 2; ++n)
#pragma unroll
    for (int kk = 0; kk < 8; ++kk)
      B2[n][kk] = *reinterpret_cast<const bf16x8*>(
          Bw2 + (size_t)(w * 32 + n * 16 + lr) * kH + kk * 32 + lg * 8);
  float b1v[4], b2v[2];
#pragma unroll
  for (int n = 0; n < 4; ++n) b1v[n] = bs1[w * 64 + n * 16 + lr];
#pragma unroll
  for (int n = 0; n < 2; ++n) b2v[n] = bs2[w * 32 + n * 16 + lr];

  // ---- prologue: gather first tile
  int t = Bi;
  int rows = min(64, gcnt - t * 64);
  int tokR[4]; float gtR[4]; uint4 R[4];
#pragma unroll
  for (int p = 0; p < 4; ++p) {
    int r = p * 16 + gr; bool v = r < rows; int bi2 = e * kT + t * 64 + r;
    tokR[p] = v ? btok[bi2] : -1;
    gtR[p]  = v ? bgate[bi2] : 0.f;
  }
#pragma unroll
  for (int p = 0; p < 4; ++p) {
    R[p] = make_uint4(0u, 0u, 0u, 0u);
    if (tokR[p] >= 0)
      R[p] = *reinterpret_cast<const uint4*>(xb + (size_t)tokR[p] * kD + gc);
  }
  int pb = 0;

  for (;;) {
    // ---- stage current tile into LDS
#pragma unroll
    for (int p = 0; p < 4; ++p)
      *reinterpret_cast<uint4*>(&xs[(p * 16 + gr) * LDX + gc]) = R[p];
    if ((tid & 15) == 0) {
#pragma unroll
      for (int p = 0; p < 4; ++p) {
        tkL[pb][p * 16 + gr] = tokR[p];
        gtL[pb][p * 16 + gr] = gtR[p];
      }
    }
    // ---- prefetch next tile's metadata
    int tn = t + Be;
    bool hasN = tn < tiles_e;
    int rowsN = 0;
    if (hasN) {
      rowsN = min(64, gcnt - tn * 64);
#pragma unroll
      for (int p = 0; p < 4; ++p) {
        int r = p * 16 + gr; bool v = r < rowsN; int bi2 = e * kT + tn * 64 + r;
        tokR[p] = v ? btok[bi2] : -1;
        gtR[p]  = v ? bgate[bi2] : 0.f;
      }
    }
    __syncthreads();

    // ---- GEMM1: h = relu(x * W1 + b1), n-split to cap acc pressure
#pragma unroll
    for (int h2 = 0; h2 < 2; ++h2) {
      f32x4 acc[4][2];
#pragma unroll
      for (int m = 0; m < 4; ++m)
#pragma unroll
        for (int n = 0; n < 2; ++n) acc[m][n] = z4;
#pragma unroll
      for (int kk = 0; kk < 4; ++kk) {
        bf16x8 a[4];
#pragma unroll
        for (int m = 0; m < 4; ++m)
          a[m] = *reinterpret_cast<const bf16x8*>(xs + (m * 16 + lr) * LDX + kk * 32 + lg * 8);
#pragma unroll
        for (int m = 0; m < 4; ++m)
#pragma unroll
          for (int n = 0; n < 2; ++n)
            acc[m][n] = __builtin_amdgcn_mfma_f32_16x16x32_bf16(a[m], B1[h2 * 2 + n][kk], acc[m][n], 0, 0, 0);
      }
#pragma unroll
      for (int n = 0; n < 2; ++n) {
        const int nn = h2 * 2 + n;
        const int h = w * 64 + nn * 16 + lr;
        const float bs = b1v[nn];
#pragma unroll
        for (int m = 0; m < 4; ++m)
#pragma unroll
          for (int q = 0; q < 4; ++q) {
            float v = acc[m][n][q] + bs;
            v = fmaxf(v, 0.f);
            hs[(m * 16 + lg * 4 + q) * LDH + h] = f2bf(v);
          }
      }
    }
    // ---- issue next tile's x gather (hides under barrier + GEMM2)
    if (hasN) {
#pragma unroll
      for (int p = 0; p < 4; ++p) {
        R[p] = make_uint4(0u, 0u, 0u, 0u);
        if (tokR[p] >= 0)
          R[p] = *reinterpret_cast<const uint4*>(xb + (size_t)tokR[p] * kD + gc);
      }
    }
    __syncthreads();

    // ---- GEMM2: eo = h * W2 (B2 in regs)
    f32x4 acc2[4][2];
#pragma unroll
    for (int m = 0; m < 4; ++m)
#pragma unroll
      for (int n = 0; n < 2; ++n) acc2[m][n] = z4;
#pragma unroll
    for (int kk = 0; kk < 8; ++kk) {
      bf16x8 a[4];
#pragma unroll
      for (int m = 0; m < 4; ++m)
        a[m] = *reinterpret_cast<const bf16x8*>(hs + (m * 16 + lr) * LDH + kk * 32 + lg * 8);
#pragma unroll
      for (int m = 0; m < 4; ++m)
#pragma unroll
        for (int n = 0; n < 2; ++n)
          acc2[m][n] = __builtin_amdgcn_mfma_f32_16x16x32_bf16(a[m], B2[n][kk], acc2[m][n], 0, 0, 0);
    }
    // ---- epilogue: PLAIN stores (g and bias folded); no atomics anywhere
    if (e < 16) {
#pragma unroll
      for (int m = 0; m < 4; ++m)
#pragma unroll
        for (int q = 0; q < 4; ++q) {
          int r = m * 16 + lg * 4 + q;
          if (r < rows) {
            float g = gtL[pb][r];
            size_t rowoff = (size_t)(eobase + t * 64 + r) * kD;
#pragma unroll
            for (int n = 0; n < 2; ++n) {
              int d = w * 32 + n * 16 + lr;
              eostore(eo + rowoff + d, g * (acc2[m][n][q] + b2v[n]));
            }
          }
        }
    } else {
      // universal bucket: sole writer of out -> direct store (covers all tokens)
#pragma unroll
      for (int m = 0; m < 4; ++m)
#pragma unroll
        for (int q = 0; q < 4; ++q) {
          int r = m * 16 + lg * 4 + q;
          if (r < rows) {
            int tk2 = tkL[pb][r];
            float g = gtL[pb][r];
#pragma unroll
            for (int n = 0; n < 2; ++n) {
              int d = w * 32 + n * 16 + lr;
              out[(size_t)tk2 * kD + d] = g * (acc2[m][n][q] + b2v[n]);
            }
          }
        }
    }
    if (!hasN) break;
    t = tn; rows = rowsN; pb ^= 1;
  }
}

// ---------- combine: out[t] += eo[slot0] + eo[slot1] ------------------------
template <typename EoT>
__global__ __launch_bounds__(256) void combine_kernel(
    const int* __restrict__ cnt, const int* __restrict__ tpos,
    const EoT* __restrict__ eo, float* __restrict__ out)
{
  __shared__ int base[16];
  const int tid = threadIdx.x;
  if (tid < 16) {
    int s = 0;
    for (int i = 0; i < tid; ++i) s += cnt[i * CNT_STRIDE];
    base[tid] = s;
  }
  __syncthreads();
  const int tk = blockIdx.x * 16 + (tid >> 4);   // 16 tokens/block
  const int c = tid & 15;                        // 8 elems/lane
  int a0 = tpos[2 * tk], a1 = tpos[2 * tk + 1];
  size_t r0 = (size_t)(base[a0 >> 16] + (a0 & 0xffff)) * kD + c * 8;
  size_t r1 = (size_t)(base[a1 >> 16] + (a1 & 0xffff)) * kD + c * 8;
  float s[8];
#pragma unroll
  for (int j = 0; j < 8; ++j) s[j] = eoload(&eo[r0 + j]) + eoload(&eo[r1 + j]);
  float4* op = reinterpret_cast<float4*>(out + (size_t)tk * kD + c * 8);
  float4 o0 = op[0], o1 = op[1];
  o0.x += s[0]; o0.y += s[1]; o0.z += s[2]; o0.w += s[3];
  o1.x += s[4]; o1.y += s[5]; o1.z += s[6]; o1.w += s[7];
  op[0] = o0; op[1] = o1;
}

// ---------- launch ---------------------------------------------------------
extern "C" void kernel_launch(void* const* d_in, const int* in_sizes, int n_in,
                              void* d_out, int out_size, void* d_ws, size_t ws_size,
                              hipStream_t stream) {
  (void)in_sizes; (void)n_in; (void)out_size;
  const float* x   = (const float*)d_in[0];
  const float* Wg  = (const float*)d_in[1];
  const float* bg  = (const float*)d_in[2];
  const float* W1  = (const float*)d_in[3];
  const float* b1  = (const float*)d_in[4];
  const float* W2  = (const float*)d_in[5];
  const float* b2  = (const float*)d_in[6];
  const float* Wu1 = (const float*)d_in[7];
  const float* bu1 = (const float*)d_in[8];
  const float* Wu2 = (const float*)d_in[9];
  const float* bu2 = (const float*)d_in[10];
  float* out = (float*)d_out;

  char* ws = (char*)d_ws;
  constexpr size_t OFF_XB    = 0;          // 8,388,608
  constexpr size_t OFF_W1T   = 8388608;    // 1,048,576
  constexpr size_t OFF_W2T   = 9437184;    // 1,048,576
  constexpr size_t OFF_WU1T  = 10485760;   // 65,536
  constexpr size_t OFF_WU2T  = 10551296;   // 65,536
  constexpr size_t OFF_CNT   = 10616832;   // 4,096
  constexpr size_t OFF_TPOS  = 10620928;   // 262,144
  constexpr size_t OFF_BTOK  = 10883072;   // 17*32768*4 = 2,228,224
  constexpr size_t OFF_BGATE = 13111296;   // 2,228,224
  constexpr size_t OFF_EO    = 15339520;   // f32: 33,554,432 | bf16: 16,777,216

  unsigned short* xb   = (unsigned short*)(ws + OFF_XB);
  unsigned short* W1t  = (unsigned short*)(ws + OFF_W1T);
  unsigned short* W2t  = (unsigned short*)(ws + OFF_W2T);
  unsigned short* Wu1t = (unsigned short*)(ws + OFF_WU1T);
  unsigned short* Wu2t = (unsigned short*)(ws + OFF_WU2T);
  int*   cnt   = (int*)(ws + OFF_CNT);
  int*   tpos  = (int*)(ws + OFF_TPOS);
  int*   btok  = (int*)(ws + OFF_BTOK);
  float* bgate = (float*)(ws + OFF_BGATE);

  hipMemsetAsync(cnt, 0, 17 * CNT_STRIDE * sizeof(int), stream);
  front_kernel<<<NB_TP + NB_GATE, 256, 0, stream>>>(
      x, Wg, bg, W1, W2, Wu1, Wu2,
      xb, W1t, W2t, Wu1t, Wu2t, cnt, btok, bgate, tpos);

  const bool f32eo = ws_size >= OFF_EO + (size_t)65536 * kD * sizeof(float);
  if (f32eo) {
    float* eo = (float*)(ws + OFF_EO);
    moe_kernel<float><<<MOE_GRID, 256, 0, stream>>>(
        xb, W1t, W2t, Wu1t, Wu2t, b1, b2, bu1, bu2, cnt, btok, bgate, eo, out);
    combine_kernel<float><<<kT / 16, 256, 0, stream>>>(cnt, tpos, eo, out);
  } else {
    unsigned short* eo = (unsigned short*)(ws + OFF_EO);
    moe_kernel<unsigned short><<<MOE_GRID, 256, 0, stream>>>(
        xb, W1t, W2t, Wu1t, Wu2t, b1, b2, bu1, bu2, cnt, btok, bgate, eo, out);
    combine_kernel<unsigned short><<<kT / 16, 256, 0, stream>>>(cnt, tpos, eo, out);
  }
}

// Round 6
// 81.338 us; speedup vs baseline: 1.4539x; 1.4539x over previous
//
#include <hip/hip_runtime.h>
#include <hip/hip_bf16.h>

constexpr int kT = 32768;   // tokens = B*N
constexpr int kD = 128;
constexpr int kH = 256;
constexpr int kE = 16;

typedef __bf16 bf16x8 __attribute__((ext_vector_type(8)));
typedef unsigned short u16x8 __attribute__((ext_vector_type(8)));
typedef float f32x4 __attribute__((ext_vector_type(4)));

#define LDX 136   // x-tile LDS row stride (ushort) = 128 + 8 pad
#define LDH 264   // h-tile LDS row stride (ushort) = 256 + 8 pad (aliased as f32[64][132])

constexpr int NB_TP   = 272;     // transpose tiles (17 W1-like + 17 W2-like, 8 each)
constexpr int NB_GATE = kT / 64; // 512
constexpr int CNT_STRIDE = 32;   // counters padded to 128 B (own cache line)
constexpr int MOE_GRID = 512;    // 2 blocks/CU resident, expert-resident persistent

__device__ __forceinline__ unsigned short f2bf(float f) {
  unsigned int u = __float_as_uint(f);
  u += 0x7FFFu + ((u >> 16) & 1u);   // round-to-nearest-even
  return (unsigned short)(u >> 16);
}
__device__ __forceinline__ void eostore4(float* p, float4 v) {
  *reinterpret_cast<float4*>(p) = v;
}
__device__ __forceinline__ void eostore4(unsigned short* p, float4 v) {
  u16x8 o; // only 4 used
  unsigned short r[4] = {f2bf(v.x), f2bf(v.y), f2bf(v.z), f2bf(v.w)};
  *reinterpret_cast<ulong1*>(p) = *reinterpret_cast<ulong1*>(r);
  (void)o;
}
__device__ __forceinline__ float eoload(const float* p) { return *p; }
__device__ __forceinline__ float eoload(const unsigned short* p) {
  unsigned int u = (unsigned int)(*p) << 16; return __uint_as_float(u);
}

// ---------- fused front-end: weight transpose | gating (+x cast, tpos) ------
__global__ __launch_bounds__(256) void front_kernel(
    const float* __restrict__ x, const float* __restrict__ Wg,
    const float* __restrict__ bg,
    const float* __restrict__ W1, const float* __restrict__ W2,
    const float* __restrict__ Wu1, const float* __restrict__ Wu2,
    unsigned short* __restrict__ xb, unsigned short* __restrict__ W1t,
    unsigned short* __restrict__ W2t, unsigned short* __restrict__ Wu1t,
    unsigned short* __restrict__ Wu2t,
    int* __restrict__ cnt, int* __restrict__ btok, float* __restrict__ bgate,
    int* __restrict__ tpos)
{
  __shared__ __align__(16) char smem[46848];
  const int tid = threadIdx.x;
  const int b = blockIdx.x;

  if (b < NB_TP) {
    // ---- LDS-tiled transpose fp32 [R][C] -> bf16 [C][R], 64x64 tiles
    int bb = b;
    const float* src; unsigned short* dst; int R, C, r0, c0;
    if (bb < 136) {                 // W1-like: [128][256] -> [256][128]
      int m = bb >> 3, t8 = bb & 7;
      R = 128; C = 256;
      src = (m < 16) ? W1 + (size_t)m * 32768 : Wu1;
      dst = (m < 16) ? W1t + (size_t)m * 32768 : Wu1t;
      r0 = (t8 & 1) * 64; c0 = (t8 >> 1) * 64;
    } else {                        // W2-like: [256][128] -> [128][256]
      bb -= 136;
      int m = bb >> 3, t8 = bb & 7;
      R = 256; C = 128;
      src = (m < 16) ? W2 + (size_t)m * 32768 : Wu2;
      dst = (m < 16) ? W2t + (size_t)m * 32768 : Wu2t;
      r0 = (t8 >> 1) * 64; c0 = (t8 & 1) * 64;
    }
    unsigned short (*tl)[72] = reinterpret_cast<unsigned short(*)[72]>(smem);
#pragma unroll
    for (int i = 0; i < 4; ++i) {
      int s = i * 256 + tid;
      int r = s >> 4, c4 = s & 15;
      float4 v = *reinterpret_cast<const float4*>(&src[(size_t)(r0 + r) * C + c0 + c4 * 4]);
      tl[c4 * 4 + 0][r] = f2bf(v.x);
      tl[c4 * 4 + 1][r] = f2bf(v.y);
      tl[c4 * 4 + 2][r] = f2bf(v.z);
      tl[c4 * 4 + 3][r] = f2bf(v.w);
    }
    __syncthreads();
#pragma unroll
    for (int i = 0; i < 2; ++i) {
      int s = i * 256 + tid;
      int c = s >> 3, seg = s & 7;
      uint4 v = *reinterpret_cast<const uint4*>(&tl[c][seg * 8]);
      *reinterpret_cast<uint4*>(&dst[(size_t)(c0 + c) * R + r0 + seg * 8]) = v;
    }
    return;
  }

  // ---- gating: logits (fp64, ILP), top-2, scatter + x cast
  {
    float* sWt = reinterpret_cast<float*>(smem);            // [16][132]
    float* sX  = reinterpret_cast<float*>(smem + 8448);     // [64][132]
    float* sL  = reinterpret_cast<float*>(smem + 42240);    // [64][17]
    int* hcnt  = reinterpret_cast<int*>(smem + 46592);      // [16]
    int* hbase = reinterpret_cast<int*>(smem + 46656);      // [16]
    int* hb16  = reinterpret_cast<int*>(smem + 46720);      // [1]
    const int t0 = (b - NB_TP) * 64;

    if (tid < kE) hcnt[tid] = 0;
    for (int i = tid; i < kD * kE; i += 256) {              // Wg[d][e] -> sWt[e][d]
      int d = i >> 4, e = i & 15;
      sWt[e * 132 + d] = Wg[i];
    }
    const float4* xv = reinterpret_cast<const float4*>(x + (size_t)t0 * kD);
    for (int i = tid; i < 64 * kD / 4; i += 256) {
      int r = i >> 5, c4 = i & 31;
      *reinterpret_cast<float4*>(&sX[r * 132 + c4 * 4]) = xv[i];
    }
    __syncthreads();

    const int e = tid & 15, tq = tid >> 4;
    const double bgd = (double)bg[e];
    const float4* wr = reinterpret_cast<const float4*>(&sWt[e * 132]);
#pragma unroll
    for (int p = 0; p < 4; ++p) {
      int tt = p * 16 + tq;
      const float4* xr = reinterpret_cast<const float4*>(&sX[tt * 132]);
      double a0 = 0.0, a1 = 0.0, a2 = 0.0, a3 = 0.0;   // 4 independent chains
#pragma unroll
      for (int d8 = 0; d8 < 8; ++d8) {
        float4 xa0 = xr[d8 * 4 + 0], wa0 = wr[d8 * 4 + 0];
        float4 xa1 = xr[d8 * 4 + 1], wa1 = wr[d8 * 4 + 1];
        float4 xa2 = xr[d8 * 4 + 2], wa2 = wr[d8 * 4 + 2];
        float4 xa3 = xr[d8 * 4 + 3], wa3 = wr[d8 * 4 + 3];
        a0 += (double)xa0.x * (double)wa0.x + (double)xa0.y * (double)wa0.y
            + (double)xa0.z * (double)wa0.z + (double)xa0.w * (double)wa0.w;
        a1 += (double)xa1.x * (double)wa1.x + (double)xa1.y * (double)wa1.y
            + (double)xa1.z * (double)wa1.z + (double)xa1.w * (double)wa1.w;
        a2 += (double)xa2.x * (double)wa2.x + (double)xa2.y * (double)wa2.y
            + (double)xa2.z * (double)wa2.z + (double)xa2.w * (double)wa2.w;
        a3 += (double)xa3.x * (double)wa3.x + (double)xa3.y * (double)wa3.y
            + (double)xa3.z * (double)wa3.z + (double)xa3.w * (double)wa3.w;
      }
      sL[tt * 17 + e] = (float)(((a0 + a1) + (a2 + a3)) + bgd);
    }
    // fold x fp32->bf16 cast here (sX already staged)
#pragma unroll
    for (int p = 0; p < 4; ++p) {
      int idx = p * 256 + tid;
      int r = idx >> 4, c8 = (idx & 15) * 8;
      const float* sp = &sX[r * 132 + c8];
      u16x8 v;
#pragma unroll
      for (int j = 0; j < 8; ++j) v[j] = f2bf(sp[j]);
      *reinterpret_cast<u16x8*>(&xb[(size_t)(t0 + r) * kD + c8]) = v;
    }
    __syncthreads();

    int e0 = 0, e1 = 0, lp0 = 0, lp1 = 0;
    float g0 = 0.f, g1 = 0.f;
    const int t = t0 + tid;
    if (tid < 64) {
      float v0 = -3.4e38f, v1 = -3.4e38f;
      for (int i = 0; i < kE; ++i) {
        float v = sL[tid * 17 + i];
        if (v > v0) { v1 = v0; e1 = e0; v0 = v; e0 = i; }
        else if (v > v1) { v1 = v; e1 = i; }
      }
      float r = expf(v1 - v0);
      g0 = 1.f / (1.f + r);
      g1 = 1.f - g0;
      lp0 = atomicAdd(&hcnt[e0], 1);
      lp1 = atomicAdd(&hcnt[e1], 1);
    }
    if (tid == 0) hb16[0] = atomicAdd(&cnt[16 * CNT_STRIDE], 64);
    __syncthreads();
    if (tid < kE)
      hbase[tid] = atomicAdd(&cnt[tid * CNT_STRIDE], hcnt[tid]);
    __syncthreads();
    if (tid < 64) {
      int p0 = hbase[e0] + lp0;
      btok[e0 * kT + p0] = t; bgate[e0 * kT + p0] = g0;
      int p1 = hbase[e1] + lp1;
      btok[e1 * kT + p1] = t; bgate[e1 * kT + p1] = g1;
      int p2 = hb16[0] + tid;                 // universal = bucket 16, weight omega
      btok[16 * kT + p2] = t; bgate[16 * kT + p2] = 1.f - g0;
      tpos[2 * t]     = (e0 << 16) | p0;      // token -> expert slots (for combine)
      tpos[2 * t + 1] = (e1 << 16) | p1;
    }
  }
}

// ---------- expert-resident MoE: streamed weights, staged coalesced stores --
template <typename EoT>
__global__ __launch_bounds__(256, 2) void moe_kernel(
    const unsigned short* __restrict__ xb,
    const unsigned short* __restrict__ W1t,
    const unsigned short* __restrict__ W2t,
    const unsigned short* __restrict__ Wu1t,
    const unsigned short* __restrict__ Wu2t,
    const float* __restrict__ b1, const float* __restrict__ b2,
    const float* __restrict__ bu1, const float* __restrict__ bu2,
    const int* __restrict__ cnt, const int* __restrict__ btok,
    const float* __restrict__ bgate,
    EoT* __restrict__ eo, float* __restrict__ out)
{
  __shared__ alignas(16) unsigned short xs[64 * LDX];
  __shared__ alignas(16) unsigned short hs[64 * LDH];   // aliased as f32[64][132] in epilogue
  __shared__ int   tkL[2][64];
  __shared__ float gtL[2][64];
  __shared__ int stl[17];
  __shared__ int sdesc[5];
  float* hsF = reinterpret_cast<float*>(hs);
  const int tid = threadIdx.x;

  // ---- per-block expert allocation: largest-remainder, redundant/deterministic
  if (tid < 17) stl[tid] = cnt[tid * CNT_STRIDE];
  __syncthreads();
  if (tid == 0) {
    int tiles[17], tot = 0;
    for (int i = 0; i < 17; ++i) { tiles[i] = (stl[i] + 63) >> 6; tot += tiles[i]; }
    const int G = MOE_GRID;
    int Be[17], rem[17], sum = 0;
    for (int i = 0; i < 17; ++i) {
      int num = G * tiles[i];
      Be[i] = num / tot;
      rem[i] = num - Be[i] * tot;
      sum += Be[i];
    }
    int R = G - sum;                 // < 17
    for (int k = 0; k < R; ++k) {
      int bi = 0, br = -1;
      for (int i = 0; i < 17; ++i)
        if (rem[i] > br) { br = rem[i]; bi = i; }
      Be[bi] += 1; rem[bi] = -1;
    }
    int bb = blockIdx.x, acc = 0, e = -1, Bi = 0, BeE = 1;
    for (int i = 0; i < 17; ++i) {
      if (bb < acc + Be[i]) { e = i; Bi = bb - acc; BeE = Be[i]; break; }
      acc += Be[i];
    }
    sdesc[0] = e; sdesc[1] = Bi;
    sdesc[2] = (e >= 0) ? ((stl[e] + 63) >> 6) : 0;
    sdesc[3] = BeE;
    int eb = 0;
    if (e >= 0 && e < 16) for (int i = 0; i < e; ++i) eb += stl[i];
    sdesc[4] = eb;                   // eo row base
  }
  __syncthreads();
  const int e = sdesc[0], Bi = sdesc[1], tiles_e = sdesc[2], Be = sdesc[3];
  const int eobase = sdesc[4];
  if (e < 0 || Bi >= tiles_e) return;
  const int gcnt = stl[e];
  const int w = tid >> 6, l = tid & 63, lr = l & 15, lg = l >> 4;
  const int gr = tid >> 4, gc = (tid & 15) * 8;
  const f32x4 z4 = {0.f, 0.f, 0.f, 0.f};

  const unsigned short* Bw1 = (e < 16) ? W1t + (size_t)e * kH * kD : Wu1t;
  const unsigned short* Bw2 = (e < 16) ? W2t + (size_t)e * kD * kH : Wu2t;
  const float* bs1 = (e < 16) ? b1 + (size_t)e * kH : bu1;
  const float* bs2 = (e < 16) ? b2 + (size_t)e * kD : bu2;
  float b1v[4], b2v[2];
#pragma unroll
  for (int n = 0; n < 4; ++n) b1v[n] = bs1[w * 64 + n * 16 + lr];
#pragma unroll
  for (int n = 0; n < 2; ++n) b2v[n] = bs2[w * 32 + n * 16 + lr];

  // ---- prologue: gather first tile
  int t = Bi;
  int rows = min(64, gcnt - t * 64);
  int tokR[4]; float gtR[4]; uint4 R[4];
#pragma unroll
  for (int p = 0; p < 4; ++p) {
    int r = p * 16 + gr; bool v = r < rows; int bi2 = e * kT + t * 64 + r;
    tokR[p] = v ? btok[bi2] : -1;
    gtR[p]  = v ? bgate[bi2] : 0.f;
  }
#pragma unroll
  for (int p = 0; p < 4; ++p) {
    R[p] = make_uint4(0u, 0u, 0u, 0u);
    if (tokR[p] >= 0)
      R[p] = *reinterpret_cast<const uint4*>(xb + (size_t)tokR[p] * kD + gc);
  }
  int pb = 0;

  for (;;) {
    // ---- stage current tile into LDS
#pragma unroll
    for (int p = 0; p < 4; ++p)
      *reinterpret_cast<uint4*>(&xs[(p * 16 + gr) * LDX + gc]) = R[p];
    if ((tid & 15) == 0) {
#pragma unroll
      for (int p = 0; p < 4; ++p) {
        tkL[pb][p * 16 + gr] = tokR[p];
        gtL[pb][p * 16 + gr] = gtR[p];
      }
    }
    // ---- prefetch next tile's metadata
    int tn = t + Be;
    bool hasN = tn < tiles_e;
    int rowsN = 0;
    if (hasN) {
      rowsN = min(64, gcnt - tn * 64);
#pragma unroll
      for (int p = 0; p < 4; ++p) {
        int r = p * 16 + gr; bool v = r < rowsN; int bi2 = e * kT + tn * 64 + r;
        tokR[p] = v ? btok[bi2] : -1;
        gtR[p]  = v ? bgate[bi2] : 0.f;
      }
    }
    __syncthreads();                                    // B1: xs ready

    // ---- GEMM1: h = relu(x * W1 + b1); n-split halves, streamed B (8 live)
#pragma unroll
    for (int h2 = 0; h2 < 2; ++h2) {
      bf16x8 bf[2][4];                                  // [n][kk] batch of 8
#pragma unroll
      for (int n = 0; n < 2; ++n)
#pragma unroll
        for (int kk = 0; kk < 4; ++kk)
          bf[n][kk] = *reinterpret_cast<const bf16x8*>(
              Bw1 + (size_t)(w * 64 + (h2 * 2 + n) * 16 + lr) * kD + kk * 32 + lg * 8);
      f32x4 acc[4][2];
#pragma unroll
      for (int m = 0; m < 4; ++m)
#pragma unroll
        for (int n = 0; n < 2; ++n) acc[m][n] = z4;
#pragma unroll
      for (int kk = 0; kk < 4; ++kk) {
        bf16x8 a[4];
#pragma unroll
        for (int m = 0; m < 4; ++m)
          a[m] = *reinterpret_cast<const bf16x8*>(xs + (m * 16 + lr) * LDX + kk * 32 + lg * 8);
#pragma unroll
        for (int m = 0; m < 4; ++m)
#pragma unroll
          for (int n = 0; n < 2; ++n)
            acc[m][n] = __builtin_amdgcn_mfma_f32_16x16x32_bf16(a[m], bf[n][kk], acc[m][n], 0, 0, 0);
      }
#pragma unroll
      for (int n = 0; n < 2; ++n) {
        const int nn = h2 * 2 + n;
        const int h = w * 64 + nn * 16 + lr;
        const float bs = b1v[nn];
#pragma unroll
        for (int m = 0; m < 4; ++m)
#pragma unroll
          for (int q = 0; q < 4; ++q) {
            float v = acc[m][n][q] + bs;
            v = fmaxf(v, 0.f);
            hs[(m * 16 + lg * 4 + q) * LDH + h] = f2bf(v);
          }
      }
    }
    // ---- issue next tile's x gather (hides under barrier + GEMM2)
    if (hasN) {
#pragma unroll
      for (int p = 0; p < 4; ++p) {
        R[p] = make_uint4(0u, 0u, 0u, 0u);
        if (tokR[p] >= 0)
          R[p] = *reinterpret_cast<const uint4*>(xb + (size_t)tokR[p] * kD + gc);
      }
    }
    __syncthreads();                                    // B2: hs ready

    // ---- GEMM2: eo = h * W2; streamed B in 2 batches of 8
    f32x4 acc2[4][2];
#pragma unroll
    for (int m = 0; m < 4; ++m)
#pragma unroll
      for (int n = 0; n < 2; ++n) acc2[m][n] = z4;
#pragma unroll
    for (int kb = 0; kb < 2; ++kb) {
      bf16x8 bf[2][4];
#pragma unroll
      for (int n = 0; n < 2; ++n)
#pragma unroll
        for (int k2 = 0; k2 < 4; ++k2)
          bf[n][k2] = *reinterpret_cast<const bf16x8*>(
              Bw2 + (size_t)(w * 32 + n * 16 + lr) * kH + (kb * 4 + k2) * 32 + lg * 8);
#pragma unroll
      for (int k2 = 0; k2 < 4; ++k2) {
        const int kk = kb * 4 + k2;
        bf16x8 a[4];
#pragma unroll
        for (int m = 0; m < 4; ++m)
          a[m] = *reinterpret_cast<const bf16x8*>(hs + (m * 16 + lr) * LDH + kk * 32 + lg * 8);
#pragma unroll
        for (int m = 0; m < 4; ++m)
#pragma unroll
          for (int n = 0; n < 2; ++n)
            acc2[m][n] = __builtin_amdgcn_mfma_f32_16x16x32_bf16(a[m], bf[n][k2], acc2[m][n], 0, 0, 0);
      }
    }
    __syncthreads();                                    // B3: all hs reads done

    // ---- epilogue stage: val = g*(acc2+b2) -> hsF[64][132] (2-way free banks)
#pragma unroll
    for (int m = 0; m < 4; ++m)
#pragma unroll
      for (int q = 0; q < 4; ++q) {
        int r = m * 16 + lg * 4 + q;
        float g = gtL[pb][r];
#pragma unroll
        for (int n = 0; n < 2; ++n)
          hsF[r * 132 + w * 32 + n * 16 + lr] = g * (acc2[m][n][q] + b2v[n]);
      }
    __syncthreads();                                    // B4: hsF ready

    // ---- coalesced store: full 512 B rows, no partial lines
    if (e < 16) {
      EoT* dst = eo + (size_t)(eobase + t * 64) * kD;
#pragma unroll
      for (int j = 0; j < 8; ++j) {
        int gidx = j * 1024 + tid * 4;
        int r = gidx >> 7, c = gidx & 127;
        if (r < rows) {
          float4 v = *reinterpret_cast<const float4*>(&hsF[r * 132 + c]);
          eostore4(dst + (size_t)r * kD + c, v);
        }
      }
    } else {
#pragma unroll
      for (int j = 0; j < 8; ++j) {
        int gidx = j * 1024 + tid * 4;
        int r = gidx >> 7, c = gidx & 127;
        if (r < rows) {
          int tok = tkL[pb][r];
          float4 v = *reinterpret_cast<const float4*>(&hsF[r * 132 + c]);
          *reinterpret_cast<float4*>(out + (size_t)tok * kD + c) = v;
        }
      }
    }
    if (!hasN) break;
    t = tn; rows = rowsN; pb ^= 1;
  }
}

// ---------- combine: out[t] += eo[slot0] + eo[slot1] ------------------------
template <typename EoT>
__global__ __launch_bounds__(256) void combine_kernel(
    const int* __restrict__ cnt, const int* __restrict__ tpos,
    const EoT* __restrict__ eo, float* __restrict__ out)
{
  __shared__ int base[16];
  const int tid = threadIdx.x;
  if (tid < 16) {
    int s = 0;
    for (int i = 0; i < tid; ++i) s += cnt[i * CNT_STRIDE];
    base[tid] = s;
  }
  __syncthreads();
  const int tk = blockIdx.x * 16 + (tid >> 4);   // 16 tokens/block
  const int c = tid & 15;                        // 8 elems/lane
  int a0 = tpos[2 * tk], a1 = tpos[2 * tk + 1];
  size_t r0 = (size_t)(base[a0 >> 16] + (a0 & 0xffff)) * kD + c * 8;
  size_t r1 = (size_t)(base[a1 >> 16] + (a1 & 0xffff)) * kD + c * 8;
  float s[8];
#pragma unroll
  for (int j = 0; j < 8; ++j) s[j] = eoload(&eo[r0 + j]) + eoload(&eo[r1 + j]);
  float4* op = reinterpret_cast<float4*>(out + (size_t)tk * kD + c * 8);
  float4 o0 = op[0], o1 = op[1];
  o0.x += s[0]; o0.y += s[1]; o0.z += s[2]; o0.w += s[3];
  o1.x += s[4]; o1.y += s[5]; o1.z += s[6]; o1.w += s[7];
  op[0] = o0; op[1] = o1;
}

// ---------- launch ---------------------------------------------------------
extern "C" void kernel_launch(void* const* d_in, const int* in_sizes, int n_in,
                              void* d_out, int out_size, void* d_ws, size_t ws_size,
                              hipStream_t stream) {
  (void)in_sizes; (void)n_in; (void)out_size;
  const float* x   = (const float*)d_in[0];
  const float* Wg  = (const float*)d_in[1];
  const float* bg  = (const float*)d_in[2];
  const float* W1  = (const float*)d_in[3];
  const float* b1  = (const float*)d_in[4];
  const float* W2  = (const float*)d_in[5];
  const float* b2  = (const float*)d_in[6];
  const float* Wu1 = (const float*)d_in[7];
  const float* bu1 = (const float*)d_in[8];
  const float* Wu2 = (const float*)d_in[9];
  const float* bu2 = (const float*)d_in[10];
  float* out = (float*)d_out;

  char* ws = (char*)d_ws;
  constexpr size_t OFF_XB    = 0;          // 8,388,608
  constexpr size_t OFF_W1T   = 8388608;    // 1,048,576
  constexpr size_t OFF_W2T   = 9437184;    // 1,048,576
  constexpr size_t OFF_WU1T  = 10485760;   // 65,536
  constexpr size_t OFF_WU2T  = 10551296;   // 65,536
  constexpr size_t OFF_CNT   = 10616832;   // 4,096
  constexpr size_t OFF_TPOS  = 10620928;   // 262,144
  constexpr size_t OFF_BTOK  = 10883072;   // 17*32768*4 = 2,228,224
  constexpr size_t OFF_BGATE = 13111296;   // 2,228,224
  constexpr size_t OFF_EO    = 15339520;   // f32: 33,554,432 | bf16: 16,777,216

  unsigned short* xb   = (unsigned short*)(ws + OFF_XB);
  unsigned short* W1t  = (unsigned short*)(ws + OFF_W1T);
  unsigned short* W2t  = (unsigned short*)(ws + OFF_W2T);
  unsigned short* Wu1t = (unsigned short*)(ws + OFF_WU1T);
  unsigned short* Wu2t = (unsigned short*)(ws + OFF_WU2T);
  int*   cnt   = (int*)(ws + OFF_CNT);
  int*   tpos  = (int*)(ws + OFF_TPOS);
  int*   btok  = (int*)(ws + OFF_BTOK);
  float* bgate = (float*)(ws + OFF_BGATE);

  hipMemsetAsync(cnt, 0, 17 * CNT_STRIDE * sizeof(int), stream);
  front_kernel<<<NB_TP + NB_GATE, 256, 0, stream>>>(
      x, Wg, bg, W1, W2, Wu1, Wu2,
      xb, W1t, W2t, Wu1t, Wu2t, cnt, btok, bgate, tpos);

  const bool f32eo = ws_size >= OFF_EO + (size_t)65536 * kD * sizeof(float);
  if (f32eo) {
    float* eo = (float*)(ws + OFF_EO);
    moe_kernel<float><<<MOE_GRID, 256, 0, stream>>>(
        xb, W1t, W2t, Wu1t, Wu2t, b1, b2, bu1, bu2, cnt, btok, bgate, eo, out);
    combine_kernel<float><<<kT / 16, 256, 0, stream>>>(cnt, tpos, eo, out);
  } else {
    unsigned short* eo = (unsigned short*)(ws + OFF_EO);
    moe_kernel<unsigned short><<<MOE_GRID, 256, 0, stream>>>(
        xb, W1t, W2t, Wu1t, Wu2t, b1, b2, bu1, bu2, cnt, btok, bgate, eo, out);
    combine_kernel<unsigned short><<<kT / 16, 256, 0, stream>>>(cnt, tpos, eo, out);
  }
}